// Round 1
// baseline (4396.936 us; speedup 1.0000x reference)
//
#include <hip/hip_runtime.h>
#include <hip/hip_bf16.h>
#include <math.h>

// Problem constants (from reference setup_inputs)
constexpr int B = 2, H = 16, T = 2048, D = 64;
constexpr float V_TH = 1.0f;
constexpr float EPS = 1e-7f;
constexpr float TAU_RC = 0.02f;
constexpr float TAU_REF = 0.002f;
constexpr float INV_TEMP = 0.125f;  // 1/sqrt(64)

// One block per (b, h, t) query row. Scores for the whole causal row live in LDS.
__global__ __launch_bounds__(256) void lif_attn_kernel(
    const float* __restrict__ Q, const float* __restrict__ V,
    const float* __restrict__ E, const float* __restrict__ gain,
    const float* __restrict__ bias, float* __restrict__ out)
{
    const int tid = threadIdx.x;
    const int idx = blockIdx.x;            // b*H*T + h*T + t
    const int t = idx & (T - 1);
    const int h = (idx >> 11) & (H - 1);
    const int b = idx >> 15;

    __shared__ float q[D];
    __shared__ float sc[T];
    __shared__ float redm[4];
    __shared__ float reds[4];
    __shared__ float part[256];

    const size_t qbase = ((size_t)(b * H + h) * T + t) * D;
    if (tid < D) q[tid] = Q[qbase + tid];
    __syncthreads();

    const float g  = gain[h * T + t];   // gain/bias broadcast over s: per-row scalars
    const float bb = bias[h * T + t];

    // ---- scores for s in [0, t] ----
    float lmax = -INFINITY;
    for (int s = tid; s <= t; s += 256) {
        const float4* e4 = reinterpret_cast<const float4*>(E + (size_t)(h * T + s) * D);
        float dot = 0.f;
        #pragma unroll
        for (int i = 0; i < 16; ++i) {
            float4 ev = e4[i];
            dot = fmaf(q[4 * i + 0], ev.x, dot);
            dot = fmaf(q[4 * i + 1], ev.y, dot);
            dot = fmaf(q[4 * i + 2], ev.z, dot);
            dot = fmaf(q[4 * i + 3], ev.w, dot);
        }
        const float I = fmaf(g, dot, bb);
        float r = 0.f;
        if (I > V_TH + EPS) {
            r = 1.0f / (TAU_REF - TAU_RC * log1pf(-V_TH / I));
        }
        const float score = r * INV_TEMP;
        sc[s] = score;
        lmax = fmaxf(lmax, score);
    }

    // ---- block max ----
    #pragma unroll
    for (int o = 32; o > 0; o >>= 1) lmax = fmaxf(lmax, __shfl_down(lmax, o));
    if ((tid & 63) == 0) redm[tid >> 6] = lmax;
    __syncthreads();
    const float m = fmaxf(fmaxf(redm[0], redm[1]), fmaxf(redm[2], redm[3]));

    // ---- exp in place + block sum ----
    float lsum = 0.f;
    for (int s = tid; s <= t; s += 256) {
        const float p = expf(sc[s] - m);
        sc[s] = p;
        lsum += p;
    }
    #pragma unroll
    for (int o = 32; o > 0; o >>= 1) lsum += __shfl_down(lsum, o);
    if ((tid & 63) == 0) reds[tid >> 6] = lsum;
    __syncthreads();
    const float inv = 1.0f / (reds[0] + reds[1] + reds[2] + reds[3]);

    // ---- PV: lane = output dim d, 4 s-chunks; coalesced V reads ----
    const int d = tid & 63;
    const int c = tid >> 6;
    float acc = 0.f;
    const float* vp = V + (size_t)(b * H + h) * T * D + d;
    for (int s = c; s <= t; s += 4) {
        acc = fmaf(sc[s], vp[(size_t)s * D], acc);
    }
    part[tid] = acc;
    __syncthreads();
    if (tid < 64) {
        const float o = (part[tid] + part[tid + 64]) + (part[tid + 128] + part[tid + 192]);
        out[qbase + tid] = o * inv;
    }
}

extern "C" void kernel_launch(void* const* d_in, const int* in_sizes, int n_in,
                              void* d_out, int out_size, void* d_ws, size_t ws_size,
                              hipStream_t stream) {
    const float* Q    = (const float*)d_in[0];
    // d_in[1] = K is UNUSED by the reference (scores use enc_hat, not K)
    const float* V    = (const float*)d_in[2];
    const float* E    = (const float*)d_in[3];
    const float* gain = (const float*)d_in[4];
    const float* bias = (const float*)d_in[5];
    float* out = (float*)d_out;

    const int grid = B * H * T;  // 65536 blocks, one per query row
    lif_attn_kernel<<<grid, 256, 0, stream>>>(Q, V, E, gain, bias, out);
}

// Round 2
// 134.088 us; speedup vs baseline: 32.7914x; 32.7914x over previous
//
#include <hip/hip_runtime.h>
#include <hip/hip_bf16.h>
#include <math.h>

constexpr int Bb = 2, Hh = 16, Tt = 2048, Dd = 64;
constexpr float TAU_RC_ = 0.02f, TAU_REF_ = 0.002f;
constexpr float INV_TEMP = 0.125f;   // 1/sqrt(64)
constexpr float SHIFT = 62.5f;       // score upper bound: (1/TAU_REF)*INV_TEMP

typedef __attribute__((ext_vector_type(8))) _Float16 f16x8;
typedef __attribute__((ext_vector_type(8))) short bf16x8;
typedef __attribute__((ext_vector_type(4))) float f32x4;

// XOR-swizzle (T2): 8-element groups within a 64-elem row, group ^= (row&7)
__device__ __forceinline__ int swzg(int row, int e0) {  // e0 8-aligned
  return row * 64 + (((e0 >> 3) ^ (row & 7)) << 3);
}
__device__ __forceinline__ int swze(int row, int e) {   // arbitrary elem
  return row * 64 + ((((e >> 3) ^ (row & 7)) << 3) | (e & 7));
}
__device__ __forceinline__ short f2bf(float x) {
  __hip_bfloat16 h = __float2bfloat16(x);
  return *reinterpret_cast<short*>(&h);
}
__device__ __forceinline__ float bf2f(short s) {
  __hip_bfloat16 h = *reinterpret_cast<__hip_bfloat16*>(&s);
  return __bfloat162float(h);
}

__global__ __launch_bounds__(256) void lif_attn_mfma(
    const float* __restrict__ Q, const float* __restrict__ V,
    const float* __restrict__ E, const float* __restrict__ gain,
    const float* __restrict__ bias, float* __restrict__ out)
{
  __shared__ _Float16 Qh[64 * 64], Ql[64 * 64];
  __shared__ _Float16 Eh[64 * 64], El[64 * 64];
  __shared__ short Vt[64 * 64];   // bf16 bits, transposed: Vt[d][s]
  __shared__ short Pl[64 * 64];   // bf16 P
  __shared__ float gk[64], bk[64];

  const int tid = threadIdx.x;
  const int bh  = blockIdx.x & 31;          // (b,h); consecutive blocks spread heads
  const int tb  = 31 - (blockIdx.x >> 5);   // big tiles dispatched first
  const int b = bh >> 4, h = bh & 15;
  const int t0 = tb * 64;

  const int lane = tid & 63, w = tid >> 6;  // wave id 0..3
  const int lrow = lane & 15, lgrp = lane >> 4;

  if (tid < 64) {
    gk[tid] = gain[h * Tt + t0 + tid];
    bk[tid] = bias[h * Tt + t0 + tid];
  }

  // ---- stage Q tile rows t0..t0+63 as f16 hi/lo (swizzled) ----
  {
    const int r = tid >> 2, c0 = (tid & 3) * 16;
    const float* src = Q + ((size_t)(b * Hh + h) * Tt + t0 + r) * 64 + c0;
    float v[16];
#pragma unroll
    for (int i = 0; i < 4; ++i) {
      float4 t4 = reinterpret_cast<const float4*>(src)[i];
      v[4 * i + 0] = t4.x; v[4 * i + 1] = t4.y; v[4 * i + 2] = t4.z; v[4 * i + 3] = t4.w;
    }
#pragma unroll
    for (int gi = 0; gi < 2; ++gi) {
      f16x8 hv, lv;
#pragma unroll
      for (int j = 0; j < 8; ++j) {
        float x = v[8 * gi + j];
        _Float16 hi = (_Float16)x;
        hv[j] = hi;
        lv[j] = (_Float16)(x - (float)hi);
      }
      int pos = swzg(r, c0 + 8 * gi);
      *reinterpret_cast<f16x8*>(&Qh[pos]) = hv;
      *reinterpret_cast<f16x8*>(&Ql[pos]) = lv;
    }
  }
  __syncthreads();

  // ---- Q fragments (loop-invariant): A-frag lane map row=lane&15, k=8*(lane>>4)+j
  f16x8 qh[2], ql[2];
#pragma unroll
  for (int kk = 0; kk < 2; ++kk) {
    int pos = swzg(16 * w + lrow, kk * 32 + 8 * lgrp);
    qh[kk] = *reinterpret_cast<const f16x8*>(&Qh[pos]);
    ql[kk] = *reinterpret_cast<const f16x8*>(&Ql[pos]);
  }

  float g4[4], b4[4];
#pragma unroll
  for (int reg = 0; reg < 4; ++reg) {
    int R = 16 * w + 4 * lgrp + reg;   // C/D layout: row=(lane>>4)*4+reg
    g4[reg] = gk[R];
    b4[reg] = bk[R];
  }

  f32x4 oacc[4] = {};
  float lpart[4] = {0.f, 0.f, 0.f, 0.f};

  for (int s0 = 0; s0 <= t0; s0 += 64) {
    // ---- stage E tile as f16 hi/lo ----
    {
      const int r = tid >> 2, c0 = (tid & 3) * 16;
      const float* src = E + ((size_t)h * Tt + s0 + r) * 64 + c0;
      float v[16];
#pragma unroll
      for (int i = 0; i < 4; ++i) {
        float4 t4 = reinterpret_cast<const float4*>(src)[i];
        v[4 * i + 0] = t4.x; v[4 * i + 1] = t4.y; v[4 * i + 2] = t4.z; v[4 * i + 3] = t4.w;
      }
#pragma unroll
      for (int gi = 0; gi < 2; ++gi) {
        f16x8 hv, lv;
#pragma unroll
        for (int j = 0; j < 8; ++j) {
          float x = v[8 * gi + j];
          _Float16 hi = (_Float16)x;
          hv[j] = hi;
          lv[j] = (_Float16)(x - (float)hi);
        }
        int pos = swzg(r, c0 + 8 * gi);
        *reinterpret_cast<f16x8*>(&Eh[pos]) = hv;
        *reinterpret_cast<f16x8*>(&El[pos]) = lv;
      }
    }
    // ---- stage V tile transposed to bf16 Vt[d][s] ----
    {
      const int s = tid >> 2, d0 = (tid & 3) * 16;
      const float* src = V + ((size_t)(b * Hh + h) * Tt + s0 + s) * 64 + d0;
#pragma unroll
      for (int i = 0; i < 4; ++i) {
        float4 t4 = reinterpret_cast<const float4*>(src)[i];
        float vv[4] = {t4.x, t4.y, t4.z, t4.w};
#pragma unroll
        for (int j = 0; j < 4; ++j) {
          int d = d0 + 4 * i + j;
          Vt[swze(d, s)] = f2bf(vv[j]);
        }
      }
    }
    __syncthreads();

    // ---- S = Q·E^T (split f16: hh + lh + hl), wave strip rows 16w..16w+15 ----
    f32x4 sacc[4] = {};
#pragma unroll
    for (int c = 0; c < 4; ++c) {
#pragma unroll
      for (int kk = 0; kk < 2; ++kk) {
        int pos = swzg(16 * c + lrow, kk * 32 + 8 * lgrp);
        f16x8 eh = *reinterpret_cast<const f16x8*>(&Eh[pos]);
        f16x8 el = *reinterpret_cast<const f16x8*>(&El[pos]);
        sacc[c] = __builtin_amdgcn_mfma_f32_16x16x32_f16(qh[kk], eh, sacc[c], 0, 0, 0);
        sacc[c] = __builtin_amdgcn_mfma_f32_16x16x32_f16(ql[kk], eh, sacc[c], 0, 0, 0);
        sacc[c] = __builtin_amdgcn_mfma_f32_16x16x32_f16(qh[kk], el, sacc[c], 0, 0, 0);
      }
    }

    // ---- LIF + fixed-shift exp -> P (bf16 LDS), accumulate row sums ----
#pragma unroll
    for (int c = 0; c < 4; ++c) {
#pragma unroll
      for (int reg = 0; reg < 4; ++reg) {
        int R = 16 * w + 4 * lgrp + reg;  // local row (t)
        int Cc = 16 * c + lrow;           // local col (s)
        float I = fmaf(g4[reg], sacc[c][reg], b4[reg]);
        float scv = 0.f;
        if (I > 1.0f + 1e-7f) {
          float L = __logf(I - 1.0f) - __logf(I);  // log1p(-1/I)
          scv = INV_TEMP / (TAU_REF_ - TAU_RC_ * L);
        }
        float p = __expf(scv - SHIFT);    // scores bounded [0, 62.5]: fixed shift
        if (s0 + Cc > t0 + R) p = 0.f;    // causal (only bites in diagonal tile)
        short pb = f2bf(p);
        lpart[reg] += bf2f(pb);           // sum exactly what PV consumes
        Pl[swze(R, Cc)] = pb;
      }
    }

    // ---- PV: oacc += P · V  (A=P rows of this wave, B=Vt) ----
#pragma unroll
    for (int c = 0; c < 4; ++c) {
#pragma unroll
      for (int kk = 0; kk < 2; ++kk) {
        bf16x8 pa = *reinterpret_cast<const bf16x8*>(&Pl[swzg(16 * w + lrow, kk * 32 + 8 * lgrp)]);
        bf16x8 vb = *reinterpret_cast<const bf16x8*>(&Vt[swzg(16 * c + lrow, kk * 32 + 8 * lgrp)]);
        oacc[c] = __builtin_amdgcn_mfma_f32_16x16x32_bf16(pa, vb, oacc[c], 0, 0, 0);
      }
    }
    __syncthreads();
  }

  // ---- finalize: row sums across the 16-lane group, divide, store ----
#pragma unroll
  for (int reg = 0; reg < 4; ++reg) {
    float l = lpart[reg];
    l += __shfl_xor(l, 1); l += __shfl_xor(l, 2);
    l += __shfl_xor(l, 4); l += __shfl_xor(l, 8);
    lpart[reg] = 1.0f / l;
  }
  float* ob = out + ((size_t)(b * Hh + h) * Tt + t0) * 64;
#pragma unroll
  for (int c = 0; c < 4; ++c) {
#pragma unroll
    for (int reg = 0; reg < 4; ++reg) {
      int R = 16 * w + 4 * lgrp + reg;
      ob[(size_t)R * 64 + 16 * c + lrow] = oacc[c][reg] * lpart[reg];
    }
  }
}

extern "C" void kernel_launch(void* const* d_in, const int* in_sizes, int n_in,
                              void* d_out, int out_size, void* d_ws, size_t ws_size,
                              hipStream_t stream) {
  const float* Q    = (const float*)d_in[0];
  // d_in[1] = K is UNUSED by the reference (scores use enc_hat)
  const float* V    = (const float*)d_in[2];
  const float* E    = (const float*)d_in[3];
  const float* gain = (const float*)d_in[4];
  const float* bias = (const float*)d_in[5];
  float* out = (float*)d_out;

  const int grid = Bb * Hh * (Tt / 64);  // 1024 blocks
  lif_attn_mfma<<<grid, 256, 0, stream>>>(Q, V, E, gain, bias, out);
}